// Round 3
// baseline (531.043 us; speedup 1.0000x reference)
//
#include <hip/hip_runtime.h>
#include <hip/hip_bf16.h>

typedef unsigned short u16;
typedef __attribute__((ext_vector_type(8))) short short8;
typedef __attribute__((ext_vector_type(4))) float floatx4;

#define NB 4
#define NT 2048
#define ND 1024
#define NH 2048
#define NO 1024
#define NE 8
#define NTOK (NB * NT)   // 8192 tokens

// 256x256-tile MoE GEMM geometry
#define BM2 256
#define BN2 256
#define BK2 32                 // u16 units; 64 B per LDS row
#define BUFU (BM2 * BK2)       // 8192 u16 = 16 KB per tile-side buffer

__device__ __forceinline__ u16 f2bf(float f) {
  __hip_bfloat16 h = __float2bfloat16(f);
  return *reinterpret_cast<u16*>(&h);
}

__device__ __forceinline__ float bf2f(unsigned u) {
  return __uint_as_float(u << 16);
}

// async 16B global->LDS (DMA: lane i lands at ldsbase + i*16)
__device__ __forceinline__ void async16(const u16* g, u16* l) {
  __builtin_amdgcn_global_load_lds(
      (const __attribute__((address_space(1))) void*)g,
      (__attribute__((address_space(3))) void*)l, 16, 0, 0);
}

// ---------------------------------------------------------------------------
// Transpose + fp32->bf16: per-expert RxC row-major -> CxR bf16.
// ---------------------------------------------------------------------------
__global__ __launch_bounds__(256) void transpose_cvt(
    const float* __restrict__ in, u16* __restrict__ out, int R, int C) {
  __shared__ float tile[64][65];
  int e = blockIdx.z;
  in  += (size_t)e * R * C;
  out += (size_t)e * R * C;
  int c0 = blockIdx.x * 64, r0 = blockIdx.y * 64;
  int t = threadIdx.x;
#pragma unroll
  for (int i = 0; i < 4; ++i) {
    int idx = t + i * 256;                  // 64 r x 16 cq
    int r = idx >> 4, cq = idx & 15;
    float4 v = *(const float4*)&in[(size_t)(r0 + r) * C + c0 + cq * 4];
    tile[r][cq * 4 + 0] = v.x; tile[r][cq * 4 + 1] = v.y;
    tile[r][cq * 4 + 2] = v.z; tile[r][cq * 4 + 3] = v.w;
  }
  __syncthreads();
#pragma unroll
  for (int i = 0; i < 4; ++i) {
    int idx = t + i * 256;                  // 64 c x 16 rq
    int c = idx >> 4, rq = idx & 15;
    uint2 p;
    p.x = (unsigned)f2bf(tile[rq * 4 + 0][c]) | ((unsigned)f2bf(tile[rq * 4 + 1][c]) << 16);
    p.y = (unsigned)f2bf(tile[rq * 4 + 2][c]) | ((unsigned)f2bf(tile[rq * 4 + 3][c]) << 16);
    *(uint2*)&out[(size_t)(c0 + c) * R + r0 + rq * 4] = p;
  }
}

// ---------------------------------------------------------------------------
// Router: 32 tokens/block, 8 lanes/token. Per-block LDS choice table;
// ONE atomicAdd per expert per block, counters padded to 128 B apart.
// ---------------------------------------------------------------------------
__global__ __launch_bounds__(256) void router_kernel(
    const float* __restrict__ x, const float* __restrict__ Wg,
    const float* __restrict__ bg, u16* __restrict__ xbf,
    int* __restrict__ counts, int* __restrict__ entries,
    float* __restrict__ wts) {
  __shared__ int   se0[32], se1[32];
  __shared__ float sw0[32], sw1[32];
  int t = threadIdx.x;
  int tl = t >> 3;                 // token slot 0..31
  int l8 = t & 7;
  int tok = blockIdx.x * 32 + tl;

  const float* xrow = x + (size_t)tok * ND;
  u16* xbrow = xbf + (size_t)tok * ND;
  float acc[8] = {};
#pragma unroll 4
  for (int i = 0; i < 32; ++i) {
    int d0 = l8 * 4 + i * 32;
    float4 xv = *(const float4*)&xrow[d0];
    uint2 p;
    p.x = (unsigned)f2bf(xv.x) | ((unsigned)f2bf(xv.y) << 16);
    p.y = (unsigned)f2bf(xv.z) | ((unsigned)f2bf(xv.w) << 16);
    *(uint2*)&xbrow[d0] = p;
    const float* wr = Wg + (size_t)d0 * NE;
#pragma unroll
    for (int j = 0; j < 4; ++j) {
      float xs = (j == 0) ? xv.x : (j == 1) ? xv.y : (j == 2) ? xv.z : xv.w;
      float4 w0 = *(const float4*)&wr[j * NE];
      float4 w1 = *(const float4*)&wr[j * NE + 4];
      acc[0] += xs * w0.x; acc[1] += xs * w0.y;
      acc[2] += xs * w0.z; acc[3] += xs * w0.w;
      acc[4] += xs * w1.x; acc[5] += xs * w1.y;
      acc[6] += xs * w1.z; acc[7] += xs * w1.w;
    }
  }
#pragma unroll
  for (int off = 4; off; off >>= 1)
#pragma unroll
    for (int k = 0; k < 8; ++k) acc[k] += __shfl_down(acc[k], off, 8);

  if (l8 == 0) {
    float best = -1e30f, second = -1e30f;
    int e0 = 0, e1 = 0;
#pragma unroll
    for (int i = 0; i < NE; ++i) {
      float L = acc[i] + bg[i];
      if (L > best) { second = best; e1 = e0; best = L; e0 = i; }
      else if (L > second) { second = L; e1 = i; }
    }
    float p1 = __expf(second - best);
    float inv = 1.f / (1.f + p1);
    se0[tl] = e0; se1[tl] = e1;
    sw0[tl] = inv; sw1[tl] = p1 * inv;
  }
  __syncthreads();

  if (t < NE) {
    int e = t;
    int c = 0;
#pragma unroll
    for (int k = 0; k < 32; ++k) c += (se0[k] == e) + (se1[k] == e);
    int pos = atomicAdd(&counts[e * 32], c);   // padded: 128 B per expert
    int base = blockIdx.x * 32;
    for (int k = 0; k < 32; ++k) {
      if (se0[k] == e) { entries[e * NTOK + pos] = (base + k) * 2;     wts[e * NTOK + pos] = sw0[k]; ++pos; }
      if (se1[k] == e) { entries[e * NTOK + pos] = (base + k) * 2 + 1; wts[e * NTOK + pos] = sw1[k]; ++pos; }
    }
  }
}

// ---------------------------------------------------------------------------
// MoE GEMM, 256x256 tile, 8 waves (2M x 4N), BK=32, TRIPLE-buffered LDS with
// counted vmcnt (T3+T4) + setprio around MFMA clusters (T5).
//
// Pipeline invariants (race-free by construction):
//  - iteration kt reads buf kt%3; stages for kt+2 go to buf (kt+2)%3, which
//    is disjoint from bufs of kt and kt+1; its previous reader (kt-1)
//    finished before iteration kt's closing barrier of kt-1.
//  - 4 global_load_lds per wave per iteration; vmcnt(4) at iteration end
//    guarantees buf (kt+1)%3 fully landed before it is read. Loads stay in
//    flight across barriers (never drained to 0 in the loop).
//  - swizzle: LDS phys 16B-chunk p of row r holds logical chunk p^((r>>1)&3);
//    DMA source pre-applies it (all row-group offsets are ≡0 mod 8 so the
//    per-lane XOR term is (lane>>3)&3 on stage, (rA>>1)&3 on read).
// ---------------------------------------------------------------------------
template<int KD, int NTILES, bool G2>
__global__ __launch_bounds__(512, 2) void gemm_moe(
    const u16* __restrict__ A, const u16* __restrict__ Bw,
    const float* __restrict__ bias, const int* __restrict__ counts,
    const int* __restrict__ entries, const float* __restrict__ wts,
    u16* __restrict__ out) {
  constexpr int LDO = NTILES * 256;   // output row length (= N of this GEMM)
  constexpr int NKT = KD / BK2;

  int b = blockIdx.x;
  int e = b & 7;                       // XCD-pinned expert
  int r = b >> 3;
  int m0 = (r / NTILES) * BM2;
  int n0 = (r % NTILES) * BN2;
  int cnt = counts[e * 32];
  if (m0 >= cnt) return;
  int rem = cnt - m0; if (rem > BM2) rem = BM2;

  __shared__ __align__(16) u16 As[3 * BUFU];   // 48 KB
  __shared__ __align__(16) u16 Bs[3 * BUFU];   // 48 KB
  __shared__ int   ent_s[BM2];
  __shared__ float w_s[BM2];

  int t = threadIdx.x;
  if (t < BM2) {
    int src = (t < rem) ? (e * NTOK + m0 + t) : (e * NTOK);
    ent_s[t] = entries[src];
    if constexpr (G2) w_s[t] = wts[src];
  }
  __syncthreads();

  int lane = t & 63, wv = t >> 6;      // wave 0..7
  int wr = wv >> 2, wc = wv & 3;       // wave output: rows wr*128.., cols wc*64..

  // ---- staging addressing: wave wv covers 16 rows per half (2 halves) ----
  int rl0 = wv * 16 + (lane >> 2);     // half-0 tile row (0..127)
  int rl1 = rl0 + 128;                 // half-1 tile row
  int chS = ((lane & 3) ^ ((lane >> 3) & 3)) * 8;  // pre-swizzled src chunk (u16)
  int eA0 = ent_s[rl0], eA1 = ent_s[rl1];
  size_t ra0 = G2 ? (size_t)eA0 : (size_t)(eA0 >> 1);
  size_t ra1 = G2 ? (size_t)eA1 : (size_t)(eA1 >> 1);
  const u16* pA0 = A + ra0 * KD + chS;
  const u16* pA1 = A + ra1 * KD + chS;
  const u16* Bbase = Bw + (size_t)e * LDO * KD + (size_t)n0 * KD;
  const u16* pB0 = Bbase + (size_t)rl0 * KD + chS;
  const u16* pB1 = Bbase + (size_t)rl1 * KD + chS;
  int dA0 = wv * 512;                  // u16 LDS offset, half 0 (wave-uniform)
  int dA1 = 4096 + wv * 512;           // half 1

  // ---- LDS fragment read offsets ----
  int rA = lane & 15, q = lane >> 4;
  int pOff = rA * BK2 + ((q ^ ((rA >> 1) & 3)) * 8);
  int aOff = wr * 4096 + pOff;         // + f*512 per 16-row fragment
  int bOff = wc * 2048 + pOff;         // + g*512

  floatx4 acc[8][4] = {};

  // ---- prologue: stage kt=0 -> buf0, kt=1 -> buf1 ----
  async16(pA0, As + 0 * BUFU + dA0);
  async16(pA1, As + 0 * BUFU + dA1);
  async16(pB0, Bs + 0 * BUFU + dA0);
  async16(pB1, Bs + 0 * BUFU + dA1);
  pA0 += BK2; pA1 += BK2; pB0 += BK2; pB1 += BK2;
  async16(pA0, As + 1 * BUFU + dA0);
  async16(pA1, As + 1 * BUFU + dA1);
  async16(pB0, Bs + 1 * BUFU + dA0);
  async16(pB1, Bs + 1 * BUFU + dA1);
  pA0 += BK2; pA1 += BK2; pB0 += BK2; pB1 += BK2;   // now at kt=2
  asm volatile("s_waitcnt vmcnt(4)" ::: "memory");  // buf0 landed
  __builtin_amdgcn_s_barrier();

  int rb = 0, sb = 2;
  for (int kt = 0; kt < NKT; ++kt) {
    const u16* Ab = As + rb * BUFU;
    const u16* Bb = Bs + rb * BUFU;
    u16* Ad = As + sb * BUFU;
    u16* Bd = Bs + sb * BUFU;
    short8 av[4], bv[4];

    // ---- phase A: m-frags 0..3 x all n ----
#pragma unroll
    for (int f = 0; f < 4; ++f) av[f] = *(const short8*)(Ab + aOff + f * 512);
#pragma unroll
    for (int g = 0; g < 4; ++g) bv[g] = *(const short8*)(Bb + bOff + g * 512);
    async16(pA0, Ad + dA0);            // stage kt+2 A halves
    async16(pA1, Ad + dA1);
    asm volatile("" ::: "memory");
    __builtin_amdgcn_s_barrier();
    __builtin_amdgcn_s_setprio(1);
#pragma unroll
    for (int f = 0; f < 4; ++f)
#pragma unroll
      for (int g = 0; g < 4; ++g)
        acc[f][g] = __builtin_amdgcn_mfma_f32_16x16x32_bf16(av[f], bv[g], acc[f][g], 0, 0, 0);
    __builtin_amdgcn_s_setprio(0);
    asm volatile("" ::: "memory");
    __builtin_amdgcn_s_barrier();

    // ---- phase B: m-frags 4..7 (B frags held in regs) ----
#pragma unroll
    for (int f = 0; f < 4; ++f) av[f] = *(const short8*)(Ab + aOff + (f + 4) * 512);
    async16(pB0, Bd + dA0);            // stage kt+2 B halves
    async16(pB1, Bd + dA1);
    asm volatile("" ::: "memory");
    __builtin_amdgcn_s_barrier();
    __builtin_amdgcn_s_setprio(1);
#pragma unroll
    for (int f = 0; f < 4; ++f)
#pragma unroll
      for (int g = 0; g < 4; ++g)
        acc[f + 4][g] = __builtin_amdgcn_mfma_f32_16x16x32_bf16(av[f], bv[g], acc[f + 4][g], 0, 0, 0);
    __builtin_amdgcn_s_setprio(0);

    if (kt + 3 < NKT) { pA0 += BK2; pA1 += BK2; pB0 += BK2; pB1 += BK2; }
    if (++rb == 3) rb = 0;
    if (++sb == 3) sb = 0;
    asm volatile("s_waitcnt vmcnt(4)" ::: "memory");  // kt+1 fully landed
    __builtin_amdgcn_s_barrier();
  }
  asm volatile("s_waitcnt vmcnt(0)" ::: "memory");    // drain tail garbage DMAs

  // ---- epilogue ----
  const float* brow = bias + (size_t)e * LDO + n0 + wc * 64;
#pragma unroll
  for (int f = 0; f < 8; ++f) {
#pragma unroll
    for (int rr = 0; rr < 4; ++rr) {
      int lm = wr * 128 + f * 16 + q * 4 + rr;
      if (lm >= rem) continue;
      int ent = ent_s[lm];
      u16* dst = out + (size_t)ent * LDO + n0 + wc * 64;
      float wgt = 1.f;
      if constexpr (G2) wgt = w_s[lm];
#pragma unroll
      for (int g = 0; g < 4; ++g) {
        int col = g * 16 + rA;
        float v = acc[f][g][rr] + brow[col];
        if constexpr (G2) v *= wgt; else v = fmaxf(v, 0.f);
        dst[col] = f2bf(v);
      }
    }
  }
}

// ---------------------------------------------------------------------------
// Combine: out[tok] = eo[2*tok] + eo[2*tok+1]
// ---------------------------------------------------------------------------
__global__ __launch_bounds__(256) void combine_kernel(
    const u16* __restrict__ eo, float* __restrict__ out) {
  size_t idx = (size_t)blockIdx.x * 256 + threadIdx.x;
  size_t tok = idx >> 8;
  int oq = (int)(idx & 255) * 4;
  const u16* p0 = eo + (tok * 2) * NO + oq;
  const u16* p1 = p0 + NO;
  uint2 ua = *(const uint2*)p0;
  uint2 ub = *(const uint2*)p1;
  float4 o;
  o.x = bf2f(ua.x & 0xffff) + bf2f(ub.x & 0xffff);
  o.y = bf2f(ua.x >> 16)    + bf2f(ub.x >> 16);
  o.z = bf2f(ua.y & 0xffff) + bf2f(ub.y & 0xffff);
  o.w = bf2f(ua.y >> 16)    + bf2f(ub.y >> 16);
  *(float4*)&out[tok * NO + oq] = o;
}

// ---------------------------------------------------------------------------
extern "C" void kernel_launch(void* const* d_in, const int* in_sizes, int n_in,
                              void* d_out, int out_size, void* d_ws, size_t ws_size,
                              hipStream_t stream) {
  (void)in_sizes; (void)n_in; (void)out_size; (void)ws_size;
  const float* x  = (const float*)d_in[0];
  const float* Wg = (const float*)d_in[2];
  const float* bg = (const float*)d_in[3];
  const float* W1 = (const float*)d_in[4];
  const float* b1 = (const float*)d_in[5];
  const float* W2 = (const float*)d_in[6];
  const float* b2 = (const float*)d_in[7];
  float* out = (float*)d_out;

  char* ws = (char*)d_ws;
  size_t off = 0;
  int*   counts  = (int*)(ws + off);   off += NE * 32 * 4;               // padded
  int*   entries = (int*)(ws + off);   off += (size_t)NE * NTOK * 4;
  float* wts     = (float*)(ws + off); off += (size_t)NE * NTOK * 4;
  u16*   xbf     = (u16*)(ws + off);   off += (size_t)NTOK * ND * 2;
  u16*   w1t     = (u16*)(ws + off);   off += (size_t)NE * NH * ND * 2;
  u16*   w2t     = (u16*)(ws + off);   off += (size_t)NE * NO * NH * 2;
  u16*   hbuf    = (u16*)(ws + off);   off += (size_t)NTOK * 2 * NH * 2;
  u16*   eo      = w1t;  // alias: w1t dead after gemm1

  hipMemsetAsync(counts, 0, NE * 32 * 4, stream);

  transpose_cvt<<<dim3(NH / 64, ND / 64, NE), 256, 0, stream>>>(W1, w1t, ND, NH);
  transpose_cvt<<<dim3(NO / 64, NH / 64, NE), 256, 0, stream>>>(W2, w2t, NH, NO);
  router_kernel<<<NTOK / 32, 256, 0, stream>>>(x, Wg, bg, xbf, counts, entries, wts);
  gemm_moe<ND, 8, false><<<NE * (NTOK / BM2) * 8, 512, 0, stream>>>(
      xbf, w1t, b1, counts, entries, wts, hbuf);
  gemm_moe<NH, 4, true ><<<NE * (NTOK / BM2) * 4, 512, 0, stream>>>(
      hbuf, w2t, b2, counts, entries, wts, eo);
  combine_kernel<<<(NTOK * NO / 4) / 256, 256, 0, stream>>>(eo, out);
}

// Round 4
// 481.282 us; speedup vs baseline: 1.1034x; 1.1034x over previous
//
#include <hip/hip_runtime.h>
#include <hip/hip_bf16.h>

typedef unsigned short u16;
typedef __attribute__((ext_vector_type(8))) short short8;
typedef __attribute__((ext_vector_type(4))) float floatx4;

#define NB 4
#define NT 2048
#define ND 1024
#define NH 2048
#define NO 1024
#define NE 8
#define NTOK (NB * NT)   // 8192 tokens

// 256x256-tile, BK=64 (K-tile), 8 waves 2M x 4N, 8-phase schedule
#define BM2 256
#define BN2 256
#define BKT 64                 // u16 per K-tile row; 128 B per LDS row
#define TBUF 16384             // u16 per (buf) = 256 rows x 64

__device__ __forceinline__ u16 f2bf(float f) {
  __hip_bfloat16 h = __float2bfloat16(f);
  return *reinterpret_cast<u16*>(&h);
}

__device__ __forceinline__ float bf2f(unsigned u) {
  return __uint_as_float(u << 16);
}

// async 16B global->LDS (DMA: lane i lands at ldsbase + i*16)
__device__ __forceinline__ void async16(const u16* g, u16* l) {
  __builtin_amdgcn_global_load_lds(
      (const __attribute__((address_space(1))) void*)g,
      (__attribute__((address_space(3))) void*)l, 16, 0, 0);
}

// ---------------------------------------------------------------------------
// Transpose + fp32->bf16: per-expert RxC row-major -> CxR bf16.
// ---------------------------------------------------------------------------
__global__ __launch_bounds__(256) void transpose_cvt(
    const float* __restrict__ in, u16* __restrict__ out, int R, int C) {
  __shared__ float tile[64][65];
  int e = blockIdx.z;
  in  += (size_t)e * R * C;
  out += (size_t)e * R * C;
  int c0 = blockIdx.x * 64, r0 = blockIdx.y * 64;
  int t = threadIdx.x;
#pragma unroll
  for (int i = 0; i < 4; ++i) {
    int idx = t + i * 256;                  // 64 r x 16 cq
    int r = idx >> 4, cq = idx & 15;
    float4 v = *(const float4*)&in[(size_t)(r0 + r) * C + c0 + cq * 4];
    tile[r][cq * 4 + 0] = v.x; tile[r][cq * 4 + 1] = v.y;
    tile[r][cq * 4 + 2] = v.z; tile[r][cq * 4 + 3] = v.w;
  }
  __syncthreads();
#pragma unroll
  for (int i = 0; i < 4; ++i) {
    int idx = t + i * 256;                  // 64 c x 16 rq
    int c = idx >> 4, rq = idx & 15;
    uint2 p;
    p.x = (unsigned)f2bf(tile[rq * 4 + 0][c]) | ((unsigned)f2bf(tile[rq * 4 + 1][c]) << 16);
    p.y = (unsigned)f2bf(tile[rq * 4 + 2][c]) | ((unsigned)f2bf(tile[rq * 4 + 3][c]) << 16);
    *(uint2*)&out[(size_t)(c0 + c) * R + r0 + rq * 4] = p;
  }
}

// ---------------------------------------------------------------------------
// Router: 32 tokens/block, 8 lanes/token.
// ---------------------------------------------------------------------------
__global__ __launch_bounds__(256) void router_kernel(
    const float* __restrict__ x, const float* __restrict__ Wg,
    const float* __restrict__ bg, u16* __restrict__ xbf,
    int* __restrict__ counts, int* __restrict__ entries,
    float* __restrict__ wts) {
  __shared__ int   se0[32], se1[32];
  __shared__ float sw0[32], sw1[32];
  int t = threadIdx.x;
  int tl = t >> 3;                 // token slot 0..31
  int l8 = t & 7;
  int tok = blockIdx.x * 32 + tl;

  const float* xrow = x + (size_t)tok * ND;
  u16* xbrow = xbf + (size_t)tok * ND;
  float acc[8] = {};
#pragma unroll 4
  for (int i = 0; i < 32; ++i) {
    int d0 = l8 * 4 + i * 32;
    float4 xv = *(const float4*)&xrow[d0];
    uint2 p;
    p.x = (unsigned)f2bf(xv.x) | ((unsigned)f2bf(xv.y) << 16);
    p.y = (unsigned)f2bf(xv.z) | ((unsigned)f2bf(xv.w) << 16);
    *(uint2*)&xbrow[d0] = p;
    const float* wr = Wg + (size_t)d0 * NE;
#pragma unroll
    for (int j = 0; j < 4; ++j) {
      float xs = (j == 0) ? xv.x : (j == 1) ? xv.y : (j == 2) ? xv.z : xv.w;
      float4 w0 = *(const float4*)&wr[j * NE];
      float4 w1 = *(const float4*)&wr[j * NE + 4];
      acc[0] += xs * w0.x; acc[1] += xs * w0.y;
      acc[2] += xs * w0.z; acc[3] += xs * w0.w;
      acc[4] += xs * w1.x; acc[5] += xs * w1.y;
      acc[6] += xs * w1.z; acc[7] += xs * w1.w;
    }
  }
#pragma unroll
  for (int off = 4; off; off >>= 1)
#pragma unroll
    for (int k = 0; k < 8; ++k) acc[k] += __shfl_down(acc[k], off, 8);

  if (l8 == 0) {
    float best = -1e30f, second = -1e30f;
    int e0 = 0, e1 = 0;
#pragma unroll
    for (int i = 0; i < NE; ++i) {
      float L = acc[i] + bg[i];
      if (L > best) { second = best; e1 = e0; best = L; e0 = i; }
      else if (L > second) { second = L; e1 = i; }
    }
    float p1 = __expf(second - best);
    float inv = 1.f / (1.f + p1);
    se0[tl] = e0; se1[tl] = e1;
    sw0[tl] = inv; sw1[tl] = p1 * inv;
  }
  __syncthreads();

  if (t < NE) {
    int e = t;
    int c = 0;
#pragma unroll
    for (int k = 0; k < 32; ++k) c += (se0[k] == e) + (se1[k] == e);
    int pos = atomicAdd(&counts[e * 32], c);   // padded: 128 B per expert
    int base = blockIdx.x * 32;
    for (int k = 0; k < 32; ++k) {
      if (se0[k] == e) { entries[e * NTOK + pos] = (base + k) * 2;     wts[e * NTOK + pos] = sw0[k]; ++pos; }
      if (se1[k] == e) { entries[e * NTOK + pos] = (base + k) * 2 + 1; wts[e * NTOK + pos] = sw1[k]; ++pos; }
    }
  }
}

// ---------------------------------------------------------------------------
// MoE GEMM, 256x256 tile, BK=64, 8 waves (2M x 4N, interleaved halves),
// 8-phase schedule (T3+T4+T5): per phase {ds_read subtile; stage 1 half-tile
// (2 DMAs/wave); barrier; 16 MFMA; barrier}, vmcnt(6) only at end of phases
// 4 and 8. LDS double-buffered (128 KB). Swizzle: phys 16B-chunk
// p = logical ^ (row&7), pre-applied on DMA source, applied on ds_read.
//
// Per-wave output: rows wr*64 + mh*128 (+f*16), cols wc*32 + nh*128 (+nf*16)
// => every wave's mh0 rows lie in staged half A0, mh1 in A1 (same for B),
// so staged halves retire early and can be re-staged mid-iteration:
//   frees: A0@ph0 B0@ph0 B1@ph1 A1@ph2 (buf0); mirrored ph4-7 (buf1)
//   stages: ph0:b1.B1 ph1:b0.A0 ph2:b0.B0 ph3:b0.A1 ph4:b0.B1
//           ph5:b1.A0 ph6:b1.B0 ph7:b1.A1   (tiles 2i+1 / 2i+2 / 2i+3)
// ---------------------------------------------------------------------------
template<int KD, int NTILES, bool G2>
__global__ __launch_bounds__(512, 2) void gemm_moe(
    const u16* __restrict__ A, const u16* __restrict__ Bw,
    const float* __restrict__ bias, const int* __restrict__ counts,
    const int* __restrict__ entries, const float* __restrict__ wts,
    u16* __restrict__ out) {
  constexpr int LDO = NTILES * 256;   // output row length (= N of this GEMM)
  constexpr int NI  = KD / 128;       // iterations (2 K-tiles each)

  int b = blockIdx.x;
  int e = b & 7;                       // XCD-pinned expert
  int r = b >> 3;
  int m0 = (r / NTILES) * BM2;
  int n0 = (r % NTILES) * BN2;
  int cnt = counts[e * 32];
  if (m0 >= cnt) return;
  int rem = cnt - m0; if (rem > BM2) rem = BM2;

  __shared__ __align__(16) u16 As[2 * TBUF];   // 64 KB
  __shared__ __align__(16) u16 Bs[2 * TBUF];   // 64 KB
  __shared__ int   ent_s[BM2];
  __shared__ float w_s[BM2];

  int t = threadIdx.x;
  if (t < BM2) {
    int src = (t < rem) ? (e * NTOK + m0 + t) : (e * NTOK);
    ent_s[t] = entries[src];
    if constexpr (G2) w_s[t] = wts[src];
  }
  __syncthreads();

  int lane = t & 63, wv = t >> 6;      // wave 0..7
  int wr = wv >> 2, wc = wv & 3;       // wave grid 2M x 4N

  // ---- staging addressing: half-tile = 128 rows; wave covers 16 rows ----
  int srow = lane >> 3;                // 0..7 within DMA's 8 rows
  int sc   = ((lane & 7) ^ (srow & 7)) * 8;   // pre-swizzled src chunk (u16)
  // A gather bases [half][dma]
  const u16* aS[2][2];
  const u16* bS[2][2];
#pragma unroll
  for (int h = 0; h < 2; ++h)
#pragma unroll
    for (int d = 0; d < 2; ++d) {
      int rowl = h * 128 + wv * 16 + d * 8 + srow;
      int ent = ent_s[rowl];
      size_t ra = G2 ? (size_t)ent : (size_t)(ent >> 1);
      aS[h][d] = A + ra * KD + sc;
      bS[h][d] = Bw + (size_t)e * LDO * KD + (size_t)(n0 + rowl) * KD + sc;
    }
  // LDS dests are wave-uniform: buf*TBUF + half*8192 + wv*1024 + dma*512

#define STAGE_A(buf, half, ko) do { int _k = (ko); if (_k >= KD) _k = 0;    \
    async16(aS[half][0] + _k, As + (buf)*TBUF + (half)*8192 + wv*1024);      \
    async16(aS[half][1] + _k, As + (buf)*TBUF + (half)*8192 + wv*1024 + 512);\
  } while (0)
#define STAGE_B(buf, half, ko) do { int _k = (ko); if (_k >= KD) _k = 0;    \
    async16(bS[half][0] + _k, Bs + (buf)*TBUF + (half)*8192 + wv*1024);      \
    async16(bS[half][1] + _k, Bs + (buf)*TBUF + (half)*8192 + wv*1024 + 512);\
  } while (0)

  // ---- LDS fragment read offsets (u16) ----
  int rA = lane & 15, q = lane >> 4;
  int aRow = (wr * 64 + rA) * 64;      // + f*1024 per 16-row frag, + mh*8192
  int bRow = (wc * 32 + rA) * 64;      // + nf*1024, + nh*8192
  int ch0 = ((q) ^ (rA & 7)) * 8;      // kstep 0 chunk (swizzled)
  int ch1 = ((4 + q) ^ (rA & 7)) * 8;  // kstep 1

  short8 a[2][4];        // [kstep][mfrag] current mh
  short8 bb[2][2][2];    // [nh][kstep][nfrag] both halves resident
  floatx4 acc[2][2][4][2] = {};   // [mh][nh][f][nf]

#define LDA(mh, buf) do {                                                   \
    const u16* _p = As + (buf)*TBUF + (mh)*8192 + aRow;                      \
    _Pragma("unroll") for (int f = 0; f < 4; ++f) {                          \
      a[0][f] = *(const short8*)(_p + f*1024 + ch0);                         \
      a[1][f] = *(const short8*)(_p + f*1024 + ch1); } } while (0)
#define LDB(nh, buf) do {                                                   \
    const u16* _p = Bs + (buf)*TBUF + (nh)*8192 + bRow;                      \
    _Pragma("unroll") for (int nf = 0; nf < 2; ++nf) {                       \
      bb[nh][0][nf] = *(const short8*)(_p + nf*1024 + ch0);                  \
      bb[nh][1][nf] = *(const short8*)(_p + nf*1024 + ch1); } } while (0)
#define MM(mh, nh)                                                           \
    __builtin_amdgcn_s_setprio(1);                                           \
    _Pragma("unroll") for (int kk = 0; kk < 2; ++kk)                         \
    _Pragma("unroll") for (int f = 0; f < 4; ++f)                            \
    _Pragma("unroll") for (int nf = 0; nf < 2; ++nf)                         \
      acc[mh][nh][f][nf] = __builtin_amdgcn_mfma_f32_16x16x32_bf16(          \
          a[kk][f], bb[nh][kk][nf], acc[mh][nh][f][nf], 0, 0, 0);            \
    __builtin_amdgcn_s_setprio(0);
#define FEN asm volatile("" ::: "memory")
#define BAR __builtin_amdgcn_s_barrier()
#define VM6 asm volatile("s_waitcnt vmcnt(6)" ::: "memory")

  // ---- prologue: tile0 -> buf0 (all 4), tile1 -> buf1 (A0,B0,A1) ----
  STAGE_A(0, 0, 0);  STAGE_B(0, 0, 0);  STAGE_A(0, 1, 0);  STAGE_B(0, 1, 0);
  STAGE_A(1, 0, 64); STAGE_B(1, 0, 64); STAGE_A(1, 1, 64);
  VM6; FEN; BAR;                        // tile0 landed

  for (int it = 0; it < NI; ++it) {
    int kb = it * 128;
    // ph0: read buf0 (mh0,nh0); stage buf1.B1 <- tile 2i+1
    LDA(0, 0); LDB(0, 0);
    STAGE_B(1, 1, 64 + kb);
    FEN; BAR;
    MM(0, 0);
    FEN; BAR;
    // ph1: (A regs reused); stage buf0.A0 <- tile 2i+2
    LDB(1, 0);
    STAGE_A(0, 0, 128 + kb);
    FEN; BAR;
    MM(0, 1);
    FEN; BAR;
    // ph2
    LDA(1, 0);
    STAGE_B(0, 0, 128 + kb);
    FEN; BAR;
    MM(1, 0);
    FEN; BAR;
    // ph3: no reads (all regs resident)
    STAGE_A(0, 1, 128 + kb);
    FEN; BAR;
    MM(1, 1);
    VM6; FEN; BAR;                      // buf1 (tile 2i+1) fully landed
    // ph4: read buf1
    LDA(0, 1); LDB(0, 1);
    STAGE_B(0, 1, 128 + kb);
    FEN; BAR;
    MM(0, 0);
    FEN; BAR;
    // ph5
    LDB(1, 1);
    STAGE_A(1, 0, 192 + kb);
    FEN; BAR;
    MM(0, 1);
    FEN; BAR;
    // ph6
    LDA(1, 1);
    STAGE_B(1, 0, 192 + kb);
    FEN; BAR;
    MM(1, 0);
    FEN; BAR;
    // ph7
    STAGE_A(1, 1, 192 + kb);
    FEN; BAR;
    MM(1, 1);
    VM6; FEN; BAR;                      // buf0 (tile 2i+2) fully landed
  }
  asm volatile("s_waitcnt vmcnt(0)" ::: "memory");   // drain tail garbage

  // ---- epilogue ----
  float bcol[2][2];
#pragma unroll
  for (int nh = 0; nh < 2; ++nh)
#pragma unroll
    for (int nf = 0; nf < 2; ++nf)
      bcol[nh][nf] = bias[e * LDO + n0 + wc * 32 + nh * 128 + nf * 16 + rA];

#pragma unroll
  for (int mh = 0; mh < 2; ++mh)
#pragma unroll
    for (int f = 0; f < 4; ++f)
#pragma unroll
      for (int rr = 0; rr < 4; ++rr) {
        int lm = wr * 64 + mh * 128 + f * 16 + q * 4 + rr;
        if (lm >= rem) continue;
        int ent = ent_s[lm];
        float wgt = 1.f;
        if constexpr (G2) wgt = w_s[lm];
        u16* dst = out + (size_t)ent * LDO + n0;
#pragma unroll
        for (int nh = 0; nh < 2; ++nh)
#pragma unroll
          for (int nf = 0; nf < 2; ++nf) {
            int col = wc * 32 + nh * 128 + nf * 16 + rA;
            float v = acc[mh][nh][f][nf][rr] + bcol[nh][nf];
            if constexpr (G2) v *= wgt; else v = fmaxf(v, 0.f);
            dst[col] = f2bf(v);
          }
      }
#undef STAGE_A
#undef STAGE_B
#undef LDA
#undef LDB
#undef MM
#undef FEN
#undef BAR
#undef VM6
}

// ---------------------------------------------------------------------------
// Combine: out[tok] = eo[2*tok] + eo[2*tok+1]
// ---------------------------------------------------------------------------
__global__ __launch_bounds__(256) void combine_kernel(
    const u16* __restrict__ eo, float* __restrict__ out) {
  size_t idx = (size_t)blockIdx.x * 256 + threadIdx.x;
  size_t tok = idx >> 8;
  int oq = (int)(idx & 255) * 4;
  const u16* p0 = eo + (tok * 2) * NO + oq;
  const u16* p1 = p0 + NO;
  uint2 ua = *(const uint2*)p0;
  uint2 ub = *(const uint2*)p1;
  float4 o;
  o.x = bf2f(ua.x & 0xffff) + bf2f(ub.x & 0xffff);
  o.y = bf2f(ua.x >> 16)    + bf2f(ub.x >> 16);
  o.z = bf2f(ua.y & 0xffff) + bf2f(ub.y & 0xffff);
  o.w = bf2f(ua.y >> 16)    + bf2f(ub.y >> 16);
  *(float4*)&out[tok * NO + oq] = o;
}

// ---------------------------------------------------------------------------
extern "C" void kernel_launch(void* const* d_in, const int* in_sizes, int n_in,
                              void* d_out, int out_size, void* d_ws, size_t ws_size,
                              hipStream_t stream) {
  (void)in_sizes; (void)n_in; (void)out_size; (void)ws_size;
  const float* x  = (const float*)d_in[0];
  const float* Wg = (const float*)d_in[2];
  const float* bg = (const float*)d_in[3];
  const float* W1 = (const float*)d_in[4];
  const float* b1 = (const float*)d_in[5];
  const float* W2 = (const float*)d_in[6];
  const float* b2 = (const float*)d_in[7];
  float* out = (float*)d_out;

  char* ws = (char*)d_ws;
  size_t off = 0;
  int*   counts  = (int*)(ws + off);   off += NE * 32 * 4;               // padded
  int*   entries = (int*)(ws + off);   off += (size_t)NE * NTOK * 4;
  float* wts     = (float*)(ws + off); off += (size_t)NE * NTOK * 4;
  u16*   xbf     = (u16*)(ws + off);   off += (size_t)NTOK * ND * 2;
  u16*   w1t     = (u16*)(ws + off);   off += (size_t)NE * NH * ND * 2;
  u16*   w2t     = (u16*)(ws + off);   off += (size_t)NE * NO * NH * 2;
  u16*   hbuf    = (u16*)(ws + off);   off += (size_t)NTOK * 2 * NH * 2;
  u16*   eo      = w1t;  // alias: w1t dead after gemm1

  hipMemsetAsync(counts, 0, NE * 32 * 4, stream);

  transpose_cvt<<<dim3(NH / 64, ND / 64, NE), 256, 0, stream>>>(W1, w1t, ND, NH);
  transpose_cvt<<<dim3(NO / 64, NH / 64, NE), 256, 0, stream>>>(W2, w2t, NH, NO);
  router_kernel<<<NTOK / 32, 256, 0, stream>>>(x, Wg, bg, xbf, counts, entries, wts);
  gemm_moe<ND, 8, false><<<NE * (NTOK / BM2) * 8, 512, 0, stream>>>(
      xbf, w1t, b1, counts, entries, wts, hbuf);
  gemm_moe<NH, 4, true ><<<NE * (NTOK / BM2) * 4, 512, 0, stream>>>(
      hbuf, w2t, b2, counts, entries, wts, eo);
  combine_kernel<<<(NTOK * NO / 4) / 256, 256, 0, stream>>>(eo, out);
}